// Round 1
// baseline (34.510 us; speedup 1.0000x reference)
//
#include <hip/hip_runtime.h>

// Problem constants (fixed by setup_inputs): B=8, L=16384, H=2, BLOCK=128, VOCAB=32000
#define NB        8
#define LLEN      16384
#define NHEAD     2
#define BLOCKSZ   128
#define VOCAB     32000
#define NBLK      (LLEN / BLOCKSZ)          // 128
#define TOKS_PER_CHUNK (BLOCKSZ * NHEAD)    // 256
#define NT_COLS   (TOKS_PER_CHUNK + LLEN * NHEAD)  // 33024 per batch row
#define NT_TOTAL  (NB * NT_COLS)            // 264192
#define CAT_TOTAL (NB * TOKS_PER_CHUNK)     // 2048
#define HIST_OFF  (NT_TOTAL + CAT_TOTAL)    // 266240

// One workgroup per (b, n) chunk: zero its 32000-float hist row, then write
// exact duplicate counts for the 256 tokens of the chunk (no atomics).
__global__ __launch_bounds__(256) void hist_kernel(const int* __restrict__ tokens,
                                                   float* __restrict__ hist) {
    __shared__ int toks[TOKS_PER_CHUNK];
    const int tid = threadIdx.x;
    const int chunk = blockIdx.x;                 // chunk = b*128 + n
    // tokens[b, n*128 .. n*128+127, 0..1] is 256 contiguous ints at chunk*256:
    // (b*16384 + n*128)*2 = (b*128 + n)*256
    toks[tid] = tokens[(size_t)chunk * TOKS_PER_CHUNK + tid];

    float* __restrict__ row = hist + (size_t)chunk * VOCAB;
    const float4 z = make_float4(0.f, 0.f, 0.f, 0.f);
    // 32000/4 = 8000 float4 stores per row
    for (int i = tid; i < VOCAB / 4; i += 256)
        reinterpret_cast<float4*>(row)[i] = z;
    __syncthreads();  // LDS visible + row fully zeroed before scatter

    const int v = toks[tid];
    int cnt = 0, first = -1;
    #pragma unroll 8
    for (int j = 0; j < TOKS_PER_CHUNK; ++j) {
        const int u = toks[j];          // broadcast read, conflict-free
        if (u == v) { cnt++; if (first < 0) first = j; }
    }
    if (first == tid) row[v] = (float)cnt;
}

// new_tokens (B x 33024) then cat_ids (B x 256), both as float.
__global__ __launch_bounds__(256) void tok_kernel(const int* __restrict__ tokens,
                                                  float* __restrict__ out) {
    const int i = blockIdx.x * 256 + threadIdx.x;
    if (i >= HIST_OFF) return;
    int v;
    if (i < NT_TOTAL) {
        const int b = i / NT_COLS;
        const int j = i - b * NT_COLS;
        if (j < TOKS_PER_CHUNK) {
            // cat part: tokens[b, (j>>1)*128, j&1]
            v = tokens[b * (LLEN * NHEAD) + ((j >> 1) << 8) + (j & 1)];
        } else {
            v = tokens[b * (LLEN * NHEAD) + (j - TOKS_PER_CHUNK)];
        }
    } else {
        const int k = i - NT_TOTAL;
        const int b = k >> 8;
        const int j = k & 255;
        v = tokens[b * (LLEN * NHEAD) + ((j >> 1) << 8) + (j & 1)];
    }
    out[i] = (float)v;
}

extern "C" void kernel_launch(void* const* d_in, const int* in_sizes, int n_in,
                              void* d_out, int out_size, void* d_ws, size_t ws_size,
                              hipStream_t stream) {
    const int* tokens = (const int*)d_in[0];
    float* out = (float*)d_out;

    tok_kernel<<<(HIST_OFF + 255) / 256, 256, 0, stream>>>(tokens, out);
    hist_kernel<<<NB * NBLK, 256, 0, stream>>>(tokens, out + HIST_OFF);
}